// Round 27
// baseline (103.917 us; speedup 1.0000x reference)
//
#include <hip/hip_runtime.h>
#include <hip/hip_bf16.h>

// FlashAttentionVarlen, bf16 32x32x16-MFMA flash attention, fp32 in/out.
// B=128 seqs (L in {128,256}), H=16, D=64, packed T=24576.
// R27 = R26 (103.9 us best) + ONE change: WAVE-DEPHASED TILE ORDER.
// All 8 waves previously computed tiles in identical order after each
// barrier (lockstep): same LDS buffer, same exp2/trans burst, same MFMA
// burst at the same time -> correlated stalls (occupancy shows ~60% of
// resident waves fully stalled). Online softmax is tile-order-invariant
// (defer-max handles any order), so waves 4-7 now sweep long-item tiles
// in swapped order (1,0 then 3,2). Each wave still reads both buffers
// between the same barriers -> WAR/visibility unchanged. Paired items
// already read disjoint buffers per wave half.
// Structure (R23/R26): persistent 512x512 work-steal, single-syncthreads
// grab (double-buffered item_s2), head-pairing for L=128 (zero idle
// waves), 4 single-use LDS tile buffers (67 KB), 2 barriers/item,
// deferred lsum cross-half combine (1 shuffle/item).
// Numerics (absmax 0.0078): K bf16-hi LDS (swizzle ^(key&7), folded bases
// idx = BASE ^ (ks<<4)), Q hi+lo regs (QK = khi*qh + khi*ql), V bf16-hi,
// P bf16-hi, swapped QK, in-register softmax, __shfl_xor(32) cross-half
// ops (raw permlane asm banned: 3 failures).

using bf16x8 = __attribute__((ext_vector_type(8))) short;
using u16x8  = __attribute__((ext_vector_type(8))) unsigned short;
using u32x4  = __attribute__((ext_vector_type(4))) unsigned;
using f32x16 = __attribute__((ext_vector_type(16))) float;

#define MFMA32(a, b, c) __builtin_amdgcn_mfma_f32_32x32x16_bf16((a), (b), (c), 0, 0, 0)

constexpr int H  = 16;
constexpr int D  = 64;
constexpr int RS = H * D;                              // packed row stride (floats)
constexpr int NITEMS = 128 * 16;                       // (b,h) work items
constexpr float QSCALE = 0.125f * 1.44269504088896f;   // 1/sqrt(64) * log2(e)
constexpr float THR    = 11.5f;                        // defer-max threshold (log2)

__device__ inline unsigned short bfbits(float x) {
  return __builtin_bit_cast(unsigned short, __float2bfloat16(x));
}
__device__ inline float bff(unsigned short u) {
  unsigned v = ((unsigned)u) << 16;
  return __builtin_bit_cast(float, v);
}
__device__ inline unsigned pack2(float x, float y) {
  return (unsigned)bfbits(x) | ((unsigned)bfbits(y) << 16);
}

__global__ __launch_bounds__(512, 2)
void fa_persist12_kernel(const float* __restrict__ qg, const float* __restrict__ kg,
                         const float* __restrict__ vg, const int* __restrict__ cu,
                         float* __restrict__ outg, int* __restrict__ ctr) {
  // 4 single-use tile buffers: K hi [key][d] (slot ^= key&7), V^T [d][key] (^= d&7)
  __shared__ unsigned short kp4[4][64 * 64];   // 32 KB
  __shared__ unsigned short vt4[4][64 * 64];   // 32 KB
  __shared__ float lsc[8 * 32];                // per-wave lane->reg bounce
  __shared__ int item_s2[2];                   // double-buffered broadcast

  const int tid = (int)threadIdx.x, lane = tid & 63, w = tid >> 6;
  const int hi = lane >> 5, qj = lane & 31;
  const bool hib = (hi != 0);

  // Folded swizzle bases: idx(row=kt*32+qj, slot=ks*2+hi) = BASE_kt ^ (ks<<4)
  const int m7   = qj & 7;
  const int boff = (hi ^ m7) << 3;
  const int KA0  = qj * 64 + boff;         // kt/n = 0 (shared by QK and PV)
  const int KA1  = (32 + qj) * 64 + boff;  // kt/n = 1

  // staging maps (512 threads: each stages 8 K-floats + 8 V-floats per tile)
  const int k_key = tid >> 3, kd0 = (tid & 7) * 8;
  const int kidx  = k_key * 64 + ((((kd0 >> 3)) ^ (k_key & 7)) << 3);
  const int v_d = tid & 63, vk0 = (tid >> 6) * 8;
  const int vidx  = v_d * 64 + ((((vk0 >> 3)) ^ (v_d & 7)) << 3);

  int parity = 0;
  for (;;) {
    // ---- grab next (b,h) item: ONE syncthreads (slot double-buffered) ----
    if (tid == 0) item_s2[parity] = atomicAdd(ctr, 1);
    __syncthreads();                     // also orders LDS buffer reuse
    const int item = item_s2[parity];
    parity ^= 1;
    if (item >= NITEMS) break;           // block-uniform exit

    const int b = item >> 4, h = item & 15;
    const int t0 = cu[b];
    const int L  = cu[b + 1] - t0;
    const bool pair = (L == 128);
    if (pair && h >= 8) continue;        // handled by item (b, h-8)

    // per-wave head / q-rows assignment (zero idle waves)
    const int myh    = pair ? ((w < 4) ? h : h + 8) : h;
    const int q_roff = pair ? (w & 3) * 32 : w * 32;
    const int hD  = h * D;
    const int h2D = (h + 8) * D;
    const int t_v1 = pair ? 0  : 64;  const int ho_v1 = pair ? h2D : hD;
    const int t_v2 = pair ? 64 : 128; const int ho_v2 = hD;
    const int t_v3 = pair ? 64 : 192; const int ho_v3 = pair ? h2D : hD;

    // ---- Q fragments FIRST (R23 order; vmcnt is FIFO) ----
    bf16x8 qh[4], ql[4];
    {
      const float* qrow = qg + (size_t)(t0 + q_roff + qj) * RS + (size_t)(myh * D);
#pragma unroll
      for (int ks = 0; ks < 4; ++ks) {
        const int d0 = ks * 16 + hi * 8;
        const float4 f0 = *reinterpret_cast<const float4*>(qrow + d0);
        const float4 f1 = *reinterpret_cast<const float4*>(qrow + d0 + 4);
        const float f[8] = {f0.x, f0.y, f0.z, f0.w, f1.x, f1.y, f1.z, f1.w};
#pragma unroll
        for (int j = 0; j < 8; ++j) {
          const float x = f[j] * QSCALE;
          const unsigned short hs = bfbits(x);
          qh[ks][j] = (short)hs;
          ql[ks][j] = (short)bfbits(x - bff(hs));
        }
      }
    }

    f32x16 acc0, acc1;
#pragma unroll
    for (int r = 0; r < 16; ++r) { acc0[r] = 0.f; acc1[r] = 0.f; }
    float m = -1e30f, lsum = 0.f;        // lsum: per-half partial (combined at epilogue)

    // ---- staging helpers ----
    auto load_t = [&](float* kf, float* vf, int tokoff, int ho) {
      const float* kr = kg + (size_t)(t0 + tokoff + k_key) * RS + (size_t)(ho + kd0);
      const float4 f0 = *reinterpret_cast<const float4*>(kr);
      const float4 f1 = *reinterpret_cast<const float4*>(kr + 4);
      kf[0] = f0.x; kf[1] = f0.y; kf[2] = f0.z; kf[3] = f0.w;
      kf[4] = f1.x; kf[5] = f1.y; kf[6] = f1.z; kf[7] = f1.w;
      const float* vp = vg + (size_t)(t0 + tokoff + vk0) * RS + (size_t)(ho + v_d);
#pragma unroll
      for (int i = 0; i < 8; ++i) vf[i] = vp[(size_t)i * RS];
    };
    auto cvt_write = [&](const float* kf, const float* vf, int buf) {
      u16x8 kh8, v8;
#pragma unroll
      for (int i = 0; i < 8; ++i) {
        kh8[i] = bfbits(kf[i]);
        v8[i]  = bfbits(vf[i]);
      }
      *reinterpret_cast<u16x8*>(&kp4[buf][kidx]) = kh8;
      *reinterpret_cast<u16x8*>(&vt4[buf][vidx]) = v8;
    };

    // ---- P pack (verified mapping; __shfl_xor only) ----
    auto mix4 = [&](unsigned a0, unsigned a1, unsigned a2, unsigned a3) -> u32x4 {
      const unsigned t02 = hib ? a0 : a2;
      const unsigned t13 = hib ? a1 : a3;
      const unsigned c02 = (unsigned)__shfl_xor((int)t02, 32);
      const unsigned c13 = (unsigned)__shfl_xor((int)t13, 32);
      u32x4 r;
      r[0] = hib ? c02 : a0;
      r[1] = hib ? c13 : a1;
      r[2] = hib ? a2 : c02;
      r[3] = hib ? a3 : c13;
      return r;
    };
    auto build_pa = [&](const float* x) -> bf16x8 {
      return __builtin_bit_cast(bf16x8,
          mix4(pack2(x[0], x[1]), pack2(x[2], x[3]),
               pack2(x[4], x[5]), pack2(x[6], x[7])));
    };

    // ---- compute one 64-key tile ----
    auto compute = [&](const unsigned short* KH, const unsigned short* VT) {
      f32x16 sc0, sc1;
#pragma unroll
      for (int r = 0; r < 16; ++r) { sc0[r] = 0.f; sc1[r] = 0.f; }
      __builtin_amdgcn_s_setprio(1);
#pragma unroll
      for (int ks = 0; ks < 4; ++ks) {
        const bf16x8 k0 = *reinterpret_cast<const bf16x8*>(&KH[KA0 ^ (ks << 4)]);
        sc0 = MFMA32(k0, qh[ks], sc0);
        sc0 = MFMA32(k0, ql[ks], sc0);
      }
#pragma unroll
      for (int ks = 0; ks < 4; ++ks) {
        const bf16x8 k1 = *reinterpret_cast<const bf16x8*>(&KH[KA1 ^ (ks << 4)]);
        sc1 = MFMA32(k1, qh[ks], sc1);
        sc1 = MFMA32(k1, ql[ks], sc1);
      }
      __builtin_amdgcn_s_setprio(0);

      float mx[8];
#pragma unroll
      for (int i = 0; i < 8; ++i) mx[i] = fmaxf(sc0[i], sc0[i + 8]);
#pragma unroll
      for (int i = 0; i < 8; ++i) mx[i] = fmaxf(mx[i], fmaxf(sc1[i], sc1[i + 8]));
#pragma unroll
      for (int i = 0; i < 4; ++i) mx[i] = fmaxf(mx[i], mx[i + 4]);
      float tmax = fmaxf(fmaxf(mx[0], mx[1]), fmaxf(mx[2], mx[3]));
      tmax = fmaxf(tmax, __shfl_xor(tmax, 32));   // m shared across halves
      if (!__all(tmax <= m + THR)) {     // first tile + rare later
        const float newm = fmaxf(m, tmax);
        const float corr = exp2f(m - newm);      // identical across lane pair
        m = newm;
        lsum *= corr;                            // per-half partial scales exactly
        if (hi == 0) lsc[w * 32 + qj] = corr;    // lane-dim -> reg-dim bounce
        __builtin_amdgcn_wave_barrier();
#pragma unroll
        for (int r = 0; r < 16; ++r) {
          const float c = lsc[w * 32 + ((r & 3) + 8 * (r >> 2) + 4 * hi)];
          acc0[r] *= c; acc1[r] *= c;
        }
      }
      float s0 = 0.f, s1 = 0.f, s2 = 0.f, s3 = 0.f;
#pragma unroll
      for (int r = 0; r < 16; r += 4) {
        sc0[r]     = exp2f(sc0[r]     - m); s0 += sc0[r];
        sc0[r + 1] = exp2f(sc0[r + 1] - m); s1 += sc0[r + 1];
        sc0[r + 2] = exp2f(sc0[r + 2] - m); s2 += sc0[r + 2];
        sc0[r + 3] = exp2f(sc0[r + 3] - m); s3 += sc0[r + 3];
      }
#pragma unroll
      for (int r = 0; r < 16; r += 4) {
        sc1[r]     = exp2f(sc1[r]     - m); s0 += sc1[r];
        sc1[r + 1] = exp2f(sc1[r + 1] - m); s1 += sc1[r + 1];
        sc1[r + 2] = exp2f(sc1[r + 2] - m); s2 += sc1[r + 2];
        sc1[r + 3] = exp2f(sc1[r + 3] - m); s3 += sc1[r + 3];
      }
      lsum += (s0 + s1) + (s2 + s3);     // own-half keys only; combine deferred

#pragma unroll
      for (int ks2 = 0; ks2 < 4; ++ks2) {
        float px[8];
#pragma unroll
        for (int i = 0; i < 8; ++i)
          px[i] = (ks2 & 2) ? sc1[(ks2 & 1) * 8 + i] : sc0[(ks2 & 1) * 8 + i];
        const bf16x8 pah = build_pa(px);
        __builtin_amdgcn_s_setprio(1);
        const bf16x8 v0 = *reinterpret_cast<const bf16x8*>(&VT[KA0 ^ (ks2 << 4)]);
        const bf16x8 v1 = *reinterpret_cast<const bf16x8*>(&VT[KA1 ^ (ks2 << 4)]);
        acc0 = MFMA32(pah, v0, acc0);
        acc1 = MFMA32(pah, v1, acc1);
        __builtin_amdgcn_s_setprio(0);
      }
    };

#define LGKM_BARRIER()                                    \
    asm volatile("s_waitcnt lgkmcnt(0)" ::: "memory");    \
    __builtin_amdgcn_s_barrier();                         \
    asm volatile("" ::: "memory")

    // ---- schedule: 4 single-use buffers, 2 barriers, zero idle waves,
    //      wave-dephased tile order (softmax is tile-order-invariant) ----
    float kfA[8], vfA[8], kfB[8], vfB[8];
    load_t(kfA, vfA, 0, hD);
    load_t(kfB, vfB, t_v1, ho_v1);
    cvt_write(kfA, vfA, 0);
    cvt_write(kfB, vfB, 1);
    LGKM_BARRIER();                      // barrier 1: bufs 0,1 visible

    if (pair) {
      load_t(kfA, vfA, t_v2, ho_v2);
      load_t(kfB, vfB, t_v3, ho_v3);
      const int c1 = (w < 4) ? 0 : 1;    // disjoint buffers per half: already dephased
      compute(kp4[c1], vt4[c1]);
      cvt_write(kfA, vfA, 2);
      cvt_write(kfB, vfB, 3);
      LGKM_BARRIER();                    // barrier 2: bufs 2,3 visible
      const int c2 = (w < 4) ? 2 : 3;
      compute(kp4[c2], vt4[c2]);
    } else {
      const int fA = (w < 4) ? 0 : 1;    // waves 0-3: 0,1 ; waves 4-7: 1,0
      const int fB = 1 - fA;
      load_t(kfA, vfA, t_v2, ho_v2);     // covered by first compute
      compute(kp4[fA], vt4[fA]);
      cvt_write(kfA, vfA, 2);
      load_t(kfB, vfB, t_v3, ho_v3);     // covered by second compute
      compute(kp4[fB], vt4[fB]);
      cvt_write(kfB, vfB, 3);
      LGKM_BARRIER();                    // barrier 2
      compute(kp4[2 + fA], vt4[2 + fA]); // waves 0-3: 2,3 ; waves 4-7: 3,2
      compute(kp4[2 + fB], vt4[2 + fB]);
    }

    // ---- epilogue: combine halves' lsum once, then normalize + store ----
    lsum += __shfl_xor(lsum, 32);        // deferred cross-half combine
    if (hi == 0) lsc[w * 32 + qj] = 1.0f / lsum;
    __builtin_amdgcn_wave_barrier();
#pragma unroll
    for (int r = 0; r < 16; ++r) {
      const int row = (r & 3) + 8 * (r >> 2) + 4 * hi;
      const float li = lsc[w * 32 + row];
      float* op = outg + (size_t)(t0 + q_roff + row) * RS + (size_t)(myh * D) + qj;
      op[0]  = acc0[r] * li;
      op[32] = acc1[r] * li;
    }
    // next grab's syncthreads orders all LDS buffer reuse across items
  }
#undef LGKM_BARRIER
}

extern "C" void kernel_launch(void* const* d_in, const int* in_sizes, int n_in,
                              void* d_out, int out_size, void* d_ws, size_t ws_size,
                              hipStream_t stream) {
  (void)in_sizes; (void)n_in; (void)ws_size; (void)out_size;
  const float* q  = (const float*)d_in[0];
  const float* k  = (const float*)d_in[1];
  const float* v  = (const float*)d_in[2];
  const int*   cu = (const int*)d_in[3];
  float* out = (float*)d_out;
  int*   ctr = (int*)d_ws;

  hipMemsetAsync(ctr, 0, sizeof(int), stream);   // work counter = 0 each launch
  // persistent: 2 blocks/CU x 256 CUs = 512 blocks, work-steal 2048 items
  fa_persist12_kernel<<<dim3(512), dim3(512), 0, stream>>>(q, k, v, cu, out, ctr);
}

// Round 28
// 102.894 us; speedup vs baseline: 1.0099x; 1.0099x over previous
//
#include <hip/hip_runtime.h>
#include <hip/hip_bf16.h>

// FlashAttentionVarlen, bf16 32x32x16-MFMA flash attention, fp32 in/out.
// B=128 seqs (L in {128,256}), H=16, D=64, packed T=24576.
// R28 = R26 (103.9 us best) + two never-isolated removals:
// (1) ALL s_setprio pairs removed (T5/m190: setprio on lockstep structures
//     is null-to-NEGATIVE — it starves co-resident waves' staging);
// (2) EARLY work-grab: item n+1's atomicAdd issues after item n's barrier
//     2, hidden under the tail computes; loop top is just syncthreads+read.
//     Race-safe: slot parity^1 last read at iter n-1 top; all threads
//     passed iter-n top syncthreads before the tail write; iter n+1 top
//     syncthreads orders write before reads. Skipped items grab inline.
// Structure (R23/R26): persistent 512x512 work-steal, head-pairing for
// L=128 (zero idle waves), 4 single-use LDS tile buffers (67 KB),
// 2 barriers/item, deferred lsum cross-half combine.
// Numerics (absmax 0.0078): K bf16-hi LDS (swizzle ^(key&7), folded bases
// idx = BASE ^ (ks<<4)), Q hi+lo regs (QK = khi*qh + khi*ql), V bf16-hi,
// P bf16-hi, swapped QK, in-register softmax, __shfl_xor(32) cross-half
// ops (raw permlane asm banned: 3 failures).

using bf16x8 = __attribute__((ext_vector_type(8))) short;
using u16x8  = __attribute__((ext_vector_type(8))) unsigned short;
using u32x4  = __attribute__((ext_vector_type(4))) unsigned;
using f32x16 = __attribute__((ext_vector_type(16))) float;

#define MFMA32(a, b, c) __builtin_amdgcn_mfma_f32_32x32x16_bf16((a), (b), (c), 0, 0, 0)

constexpr int H  = 16;
constexpr int D  = 64;
constexpr int RS = H * D;                              // packed row stride (floats)
constexpr int NITEMS = 128 * 16;                       // (b,h) work items
constexpr float QSCALE = 0.125f * 1.44269504088896f;   // 1/sqrt(64) * log2(e)
constexpr float THR    = 11.5f;                        // defer-max threshold (log2)

__device__ inline unsigned short bfbits(float x) {
  return __builtin_bit_cast(unsigned short, __float2bfloat16(x));
}
__device__ inline float bff(unsigned short u) {
  unsigned v = ((unsigned)u) << 16;
  return __builtin_bit_cast(float, v);
}
__device__ inline unsigned pack2(float x, float y) {
  return (unsigned)bfbits(x) | ((unsigned)bfbits(y) << 16);
}

__global__ __launch_bounds__(512, 2)
void fa_persist13_kernel(const float* __restrict__ qg, const float* __restrict__ kg,
                         const float* __restrict__ vg, const int* __restrict__ cu,
                         float* __restrict__ outg, int* __restrict__ ctr) {
  // 4 single-use tile buffers: K hi [key][d] (slot ^= key&7), V^T [d][key] (^= d&7)
  __shared__ unsigned short kp4[4][64 * 64];   // 32 KB
  __shared__ unsigned short vt4[4][64 * 64];   // 32 KB
  __shared__ float lsc[8 * 32];                // per-wave lane->reg bounce
  __shared__ int item_s2[2];                   // double-buffered broadcast

  const int tid = (int)threadIdx.x, lane = tid & 63, w = tid >> 6;
  const int hi = lane >> 5, qj = lane & 31;
  const bool hib = (hi != 0);

  // Folded swizzle bases: idx(row=kt*32+qj, slot=ks*2+hi) = BASE_kt ^ (ks<<4)
  const int m7   = qj & 7;
  const int boff = (hi ^ m7) << 3;
  const int KA0  = qj * 64 + boff;         // kt/n = 0 (shared by QK and PV)
  const int KA1  = (32 + qj) * 64 + boff;  // kt/n = 1

  // staging maps (512 threads: each stages 8 K-floats + 8 V-floats per tile)
  const int k_key = tid >> 3, kd0 = (tid & 7) * 8;
  const int kidx  = k_key * 64 + ((((kd0 >> 3)) ^ (k_key & 7)) << 3);
  const int v_d = tid & 63, vk0 = (tid >> 6) * 8;
  const int vidx  = v_d * 64 + ((((vk0 >> 3)) ^ (v_d & 7)) << 3);

  // initial grab into slot 0
  if (tid == 0) item_s2[0] = atomicAdd(ctr, 1);
  int parity = 0;

  for (;;) {
    __syncthreads();                     // orders grab write + LDS buffer reuse
    const int item = item_s2[parity];
    if (item >= NITEMS) break;           // block-uniform exit

    const int b = item >> 4, h = item & 15;
    const int t0 = cu[b];
    const int L  = cu[b + 1] - t0;
    const bool pair = (L == 128);
    if (pair && h >= 8) {                // handled by (b, h-8): grab + skip
      if (tid == 0) item_s2[parity ^ 1] = atomicAdd(ctr, 1);
      parity ^= 1;
      continue;
    }

    // per-wave head / q-rows assignment (zero idle waves)
    const int myh    = pair ? ((w < 4) ? h : h + 8) : h;
    const int q_roff = pair ? (w & 3) * 32 : w * 32;
    const int hD  = h * D;
    const int h2D = (h + 8) * D;
    const int t_v1 = pair ? 0  : 64;  const int ho_v1 = pair ? h2D : hD;
    const int t_v2 = pair ? 64 : 128; const int ho_v2 = hD;
    const int t_v3 = pair ? 64 : 192; const int ho_v3 = pair ? h2D : hD;

    // ---- Q fragments FIRST (vmcnt is FIFO) ----
    bf16x8 qh[4], ql[4];
    {
      const float* qrow = qg + (size_t)(t0 + q_roff + qj) * RS + (size_t)(myh * D);
#pragma unroll
      for (int ks = 0; ks < 4; ++ks) {
        const int d0 = ks * 16 + hi * 8;
        const float4 f0 = *reinterpret_cast<const float4*>(qrow + d0);
        const float4 f1 = *reinterpret_cast<const float4*>(qrow + d0 + 4);
        const float f[8] = {f0.x, f0.y, f0.z, f0.w, f1.x, f1.y, f1.z, f1.w};
#pragma unroll
        for (int j = 0; j < 8; ++j) {
          const float x = f[j] * QSCALE;
          const unsigned short hs = bfbits(x);
          qh[ks][j] = (short)hs;
          ql[ks][j] = (short)bfbits(x - bff(hs));
        }
      }
    }

    f32x16 acc0, acc1;
#pragma unroll
    for (int r = 0; r < 16; ++r) { acc0[r] = 0.f; acc1[r] = 0.f; }
    float m = -1e30f, lsum = 0.f;        // lsum: per-half partial (combined at epilogue)

    // ---- staging helpers ----
    auto load_t = [&](float* kf, float* vf, int tokoff, int ho) {
      const float* kr = kg + (size_t)(t0 + tokoff + k_key) * RS + (size_t)(ho + kd0);
      const float4 f0 = *reinterpret_cast<const float4*>(kr);
      const float4 f1 = *reinterpret_cast<const float4*>(kr + 4);
      kf[0] = f0.x; kf[1] = f0.y; kf[2] = f0.z; kf[3] = f0.w;
      kf[4] = f1.x; kf[5] = f1.y; kf[6] = f1.z; kf[7] = f1.w;
      const float* vp = vg + (size_t)(t0 + tokoff + vk0) * RS + (size_t)(ho + v_d);
#pragma unroll
      for (int i = 0; i < 8; ++i) vf[i] = vp[(size_t)i * RS];
    };
    auto cvt_write = [&](const float* kf, const float* vf, int buf) {
      u16x8 kh8, v8;
#pragma unroll
      for (int i = 0; i < 8; ++i) {
        kh8[i] = bfbits(kf[i]);
        v8[i]  = bfbits(vf[i]);
      }
      *reinterpret_cast<u16x8*>(&kp4[buf][kidx]) = kh8;
      *reinterpret_cast<u16x8*>(&vt4[buf][vidx]) = v8;
    };

    // ---- P pack (verified mapping; __shfl_xor only) ----
    auto mix4 = [&](unsigned a0, unsigned a1, unsigned a2, unsigned a3) -> u32x4 {
      const unsigned t02 = hib ? a0 : a2;
      const unsigned t13 = hib ? a1 : a3;
      const unsigned c02 = (unsigned)__shfl_xor((int)t02, 32);
      const unsigned c13 = (unsigned)__shfl_xor((int)t13, 32);
      u32x4 r;
      r[0] = hib ? c02 : a0;
      r[1] = hib ? c13 : a1;
      r[2] = hib ? a2 : c02;
      r[3] = hib ? a3 : c13;
      return r;
    };
    auto build_pa = [&](const float* x) -> bf16x8 {
      return __builtin_bit_cast(bf16x8,
          mix4(pack2(x[0], x[1]), pack2(x[2], x[3]),
               pack2(x[4], x[5]), pack2(x[6], x[7])));
    };

    // ---- compute one 64-key tile (no setprio) ----
    auto compute = [&](const unsigned short* KH, const unsigned short* VT) {
      f32x16 sc0, sc1;
#pragma unroll
      for (int r = 0; r < 16; ++r) { sc0[r] = 0.f; sc1[r] = 0.f; }
#pragma unroll
      for (int ks = 0; ks < 4; ++ks) {
        const bf16x8 k0 = *reinterpret_cast<const bf16x8*>(&KH[KA0 ^ (ks << 4)]);
        sc0 = MFMA32(k0, qh[ks], sc0);
        sc0 = MFMA32(k0, ql[ks], sc0);
      }
#pragma unroll
      for (int ks = 0; ks < 4; ++ks) {
        const bf16x8 k1 = *reinterpret_cast<const bf16x8*>(&KH[KA1 ^ (ks << 4)]);
        sc1 = MFMA32(k1, qh[ks], sc1);
        sc1 = MFMA32(k1, ql[ks], sc1);
      }

      float mx[8];
#pragma unroll
      for (int i = 0; i < 8; ++i) mx[i] = fmaxf(sc0[i], sc0[i + 8]);
#pragma unroll
      for (int i = 0; i < 8; ++i) mx[i] = fmaxf(mx[i], fmaxf(sc1[i], sc1[i + 8]));
#pragma unroll
      for (int i = 0; i < 4; ++i) mx[i] = fmaxf(mx[i], mx[i + 4]);
      float tmax = fmaxf(fmaxf(mx[0], mx[1]), fmaxf(mx[2], mx[3]));
      tmax = fmaxf(tmax, __shfl_xor(tmax, 32));   // m shared across halves
      if (!__all(tmax <= m + THR)) {     // first tile + rare later
        const float newm = fmaxf(m, tmax);
        const float corr = exp2f(m - newm);      // identical across lane pair
        m = newm;
        lsum *= corr;                            // per-half partial scales exactly
        if (hi == 0) lsc[w * 32 + qj] = corr;    // lane-dim -> reg-dim bounce
        __builtin_amdgcn_wave_barrier();
#pragma unroll
        for (int r = 0; r < 16; ++r) {
          const float c = lsc[w * 32 + ((r & 3) + 8 * (r >> 2) + 4 * hi)];
          acc0[r] *= c; acc1[r] *= c;
        }
      }
      float s0 = 0.f, s1 = 0.f, s2 = 0.f, s3 = 0.f;
#pragma unroll
      for (int r = 0; r < 16; r += 4) {
        sc0[r]     = exp2f(sc0[r]     - m); s0 += sc0[r];
        sc0[r + 1] = exp2f(sc0[r + 1] - m); s1 += sc0[r + 1];
        sc0[r + 2] = exp2f(sc0[r + 2] - m); s2 += sc0[r + 2];
        sc0[r + 3] = exp2f(sc0[r + 3] - m); s3 += sc0[r + 3];
      }
#pragma unroll
      for (int r = 0; r < 16; r += 4) {
        sc1[r]     = exp2f(sc1[r]     - m); s0 += sc1[r];
        sc1[r + 1] = exp2f(sc1[r + 1] - m); s1 += sc1[r + 1];
        sc1[r + 2] = exp2f(sc1[r + 2] - m); s2 += sc1[r + 2];
        sc1[r + 3] = exp2f(sc1[r + 3] - m); s3 += sc1[r + 3];
      }
      lsum += (s0 + s1) + (s2 + s3);     // own-half keys only; combine deferred

#pragma unroll
      for (int ks2 = 0; ks2 < 4; ++ks2) {
        float px[8];
#pragma unroll
        for (int i = 0; i < 8; ++i)
          px[i] = (ks2 & 2) ? sc1[(ks2 & 1) * 8 + i] : sc0[(ks2 & 1) * 8 + i];
        const bf16x8 pah = build_pa(px);
        const bf16x8 v0 = *reinterpret_cast<const bf16x8*>(&VT[KA0 ^ (ks2 << 4)]);
        const bf16x8 v1 = *reinterpret_cast<const bf16x8*>(&VT[KA1 ^ (ks2 << 4)]);
        acc0 = MFMA32(pah, v0, acc0);
        acc1 = MFMA32(pah, v1, acc1);
      }
    };

#define LGKM_BARRIER()                                    \
    asm volatile("s_waitcnt lgkmcnt(0)" ::: "memory");    \
    __builtin_amdgcn_s_barrier();                         \
    asm volatile("" ::: "memory")

    // ---- schedule: 4 single-use buffers, 2 barriers, zero idle waves ----
    float kfA[8], vfA[8], kfB[8], vfB[8];
    load_t(kfA, vfA, 0, hD);
    load_t(kfB, vfB, t_v1, ho_v1);
    cvt_write(kfA, vfA, 0);
    cvt_write(kfB, vfB, 1);
    LGKM_BARRIER();                      // barrier 1: bufs 0,1 visible

    if (pair) {
      load_t(kfA, vfA, t_v2, ho_v2);
      load_t(kfB, vfB, t_v3, ho_v3);
      const int c1 = (w < 4) ? 0 : 1;
      compute(kp4[c1], vt4[c1]);
      cvt_write(kfA, vfA, 2);
      cvt_write(kfB, vfB, 3);
      LGKM_BARRIER();                    // barrier 2: bufs 2,3 visible
      if (tid == 0) item_s2[parity ^ 1] = atomicAdd(ctr, 1);  // early grab
      const int c2 = (w < 4) ? 2 : 3;
      compute(kp4[c2], vt4[c2]);
    } else {
      load_t(kfA, vfA, t_v2, ho_v2);     // covered by compute(buf0)
      compute(kp4[0], vt4[0]);
      cvt_write(kfA, vfA, 2);
      load_t(kfB, vfB, t_v3, ho_v3);     // covered by compute(buf1)
      compute(kp4[1], vt4[1]);
      cvt_write(kfB, vfB, 3);
      LGKM_BARRIER();                    // barrier 2
      if (tid == 0) item_s2[parity ^ 1] = atomicAdd(ctr, 1);  // early grab
      compute(kp4[2], vt4[2]);
      compute(kp4[3], vt4[3]);
    }

    // ---- epilogue: combine halves' lsum once, then normalize + store ----
    lsum += __shfl_xor(lsum, 32);        // deferred cross-half combine
    if (hi == 0) lsc[w * 32 + qj] = 1.0f / lsum;
    __builtin_amdgcn_wave_barrier();
#pragma unroll
    for (int r = 0; r < 16; ++r) {
      const int row = (r & 3) + 8 * (r >> 2) + 4 * hi;
      const float li = lsc[w * 32 + row];
      float* op = outg + (size_t)(t0 + q_roff + row) * RS + (size_t)(myh * D) + qj;
      op[0]  = acc0[r] * li;
      op[32] = acc1[r] * li;
    }
    parity ^= 1;
    // next loop-top syncthreads orders the early-grab write + buffer reuse
  }
#undef LGKM_BARRIER
}

extern "C" void kernel_launch(void* const* d_in, const int* in_sizes, int n_in,
                              void* d_out, int out_size, void* d_ws, size_t ws_size,
                              hipStream_t stream) {
  (void)in_sizes; (void)n_in; (void)ws_size; (void)out_size;
  const float* q  = (const float*)d_in[0];
  const float* k  = (const float*)d_in[1];
  const float* v  = (const float*)d_in[2];
  const int*   cu = (const int*)d_in[3];
  float* out = (float*)d_out;
  int*   ctr = (int*)d_ws;

  hipMemsetAsync(ctr, 0, sizeof(int), stream);   // work counter = 0 each launch
  // persistent: 2 blocks/CU x 256 CUs = 512 blocks, work-steal 2048 items
  fa_persist13_kernel<<<dim3(512), dim3(512), 0, stream>>>(q, k, v, cu, out, ctr);
}